// Round 4
// baseline (594.132 us; speedup 1.0000x reference)
//
#include <hip/hip_runtime.h>

// MultiHeadAttention: B=2, S=2048, D=1024, H=16, DK=64, causal.
// Dtype model (R3-confirmed): inputs fp32; OUTPUT fp32 (bf16 label = lenient
//   comparison mode, not output dtype). Intermediates bf16 in d_ws (32MB).
// Pipeline: 3x proj GEMM (fp32->bf16) -> flash attention (bf16) ->
//   output GEMM (bf16 x fp32W -> fp32 out).

typedef short v8s __attribute__((ext_vector_type(8)));   // 8 x bf16 (4 VGPRs)
typedef float v4f __attribute__((ext_vector_type(4)));   // MFMA accumulator

#define S_LEN 2048
#define D_DIM 1024
#define NHEAD 16
#define DK 64
#define M_ROWS 4096   // B*S
#define NEG_BIG -30000.0f

__device__ inline float bf2f(unsigned short u) {
    unsigned x = ((unsigned)u) << 16;
    float f;
    __builtin_memcpy(&f, &x, 4);
    return f;
}

__device__ inline unsigned short f2bf(float f) {
    unsigned x;
    __builtin_memcpy(&x, &f, 4);
    unsigned r = x + 0x7fffu + ((x >> 16) & 1u);  // round-to-nearest-even
    return (unsigned short)(r >> 16);
}

// ---------------------------------------------------------------------------
// GEMM: out[M x 1024] = X[M x 1024] @ W[1024 x 1024] + bias -> bf16.
// X, W, bias fp32. 128x128 tile, BK=32, 4 waves.
// ---------------------------------------------------------------------------
__global__ __launch_bounds__(256) void gemm_bias_f32(
    const float* __restrict__ X,
    const float* __restrict__ W,
    const float* __restrict__ bias,
    unsigned short* __restrict__ out)
{
    __shared__ unsigned short lds_a[128 * 40];  // A tile [m][k] bf16, stride 40
    __shared__ unsigned short lds_b[128 * 40];  // W tile transposed [n][k] bf16

    const int tid  = threadIdx.x;
    const int lane = tid & 63;
    const int wave = tid >> 6;
    const int wm   = wave >> 1;
    const int wn   = wave & 1;
    const int quad = lane >> 4;
    const int col  = lane & 15;
    const int m0   = blockIdx.y * 128;
    const int n0   = blockIdx.x * 128;

    v4f acc[4][4];
#pragma unroll
    for (int i = 0; i < 4; i++)
#pragma unroll
        for (int j = 0; j < 4; j++)
#pragma unroll
            for (int r = 0; r < 4; r++) acc[i][j][r] = 0.0f;

    const int arow   = tid >> 1;          // 0..127
    const int achunk = (tid & 1) * 16;    // 0 / 16
    const int bk     = tid >> 4;          // 0..15
    const int bn     = (tid & 15) * 8;    // 0..120

    for (int k0 = 0; k0 < D_DIM; k0 += 32) {
        __syncthreads();
        // stage A (128x32 fp32 -> bf16)
        {
            const float* src = X + (size_t)(m0 + arow) * D_DIM + k0 + achunk;
            float4 f0 = *(const float4*)(src);
            float4 f1 = *(const float4*)(src + 4);
            float4 f2 = *(const float4*)(src + 8);
            float4 f3 = *(const float4*)(src + 12);
            v8s p0, p1;
            p0[0]=(short)f2bf(f0.x); p0[1]=(short)f2bf(f0.y); p0[2]=(short)f2bf(f0.z); p0[3]=(short)f2bf(f0.w);
            p0[4]=(short)f2bf(f1.x); p0[5]=(short)f2bf(f1.y); p0[6]=(short)f2bf(f1.z); p0[7]=(short)f2bf(f1.w);
            p1[0]=(short)f2bf(f2.x); p1[1]=(short)f2bf(f2.y); p1[2]=(short)f2bf(f2.z); p1[3]=(short)f2bf(f2.w);
            p1[4]=(short)f2bf(f3.x); p1[5]=(short)f2bf(f3.y); p1[6]=(short)f2bf(f3.z); p1[7]=(short)f2bf(f3.w);
            *(v8s*)(lds_a + arow * 40 + achunk)     = p0;
            *(v8s*)(lds_a + arow * 40 + achunk + 8) = p1;
        }
        // stage W transposed (32x128 fp32 -> [n][k] bf16)
        {
            const float* s0 = W + (size_t)(k0 + bk) * D_DIM + n0 + bn;
            const float* s1 = W + (size_t)(k0 + bk + 16) * D_DIM + n0 + bn;
            float4 a0 = *(const float4*)(s0);
            float4 a1 = *(const float4*)(s0 + 4);
            float4 b0 = *(const float4*)(s1);
            float4 b1 = *(const float4*)(s1 + 4);
            float e0[8] = {a0.x,a0.y,a0.z,a0.w,a1.x,a1.y,a1.z,a1.w};
            float e1[8] = {b0.x,b0.y,b0.z,b0.w,b1.x,b1.y,b1.z,b1.w};
#pragma unroll
            for (int e = 0; e < 8; e++) {
                lds_b[(bn + e) * 40 + bk]      = f2bf(e0[e]);
                lds_b[(bn + e) * 40 + bk + 16] = f2bf(e1[e]);
            }
        }
        __syncthreads();

        v8s af[4], bf[4];
#pragma unroll
        for (int mt = 0; mt < 4; mt++)
            af[mt] = *(const v8s*)(lds_a + (wm * 64 + mt * 16 + col) * 40 + quad * 8);
#pragma unroll
        for (int nt = 0; nt < 4; nt++)
            bf[nt] = *(const v8s*)(lds_b + (wn * 64 + nt * 16 + col) * 40 + quad * 8);

#pragma unroll
        for (int mt = 0; mt < 4; mt++)
#pragma unroll
            for (int nt = 0; nt < 4; nt++)
                acc[mt][nt] = __builtin_amdgcn_mfma_f32_16x16x32_bf16(
                    af[mt], bf[nt], acc[mt][nt], 0, 0, 0);
    }

    float bvv[4];
#pragma unroll
    for (int nt = 0; nt < 4; nt++)
        bvv[nt] = bias[n0 + wn * 64 + nt * 16 + col];

#pragma unroll
    for (int mt = 0; mt < 4; mt++) {
#pragma unroll
        for (int nt = 0; nt < 4; nt++) {
#pragma unroll
            for (int r = 0; r < 4; r++) {
                int row = m0 + wm * 64 + mt * 16 + quad * 4 + r;
                int c   = n0 + wn * 64 + nt * 16 + col;
                out[(size_t)row * D_DIM + c] = f2bf(acc[mt][nt][r] + bvv[nt]);
            }
        }
    }
}

// Final GEMM: X bf16 (attention out), W/bias fp32, OUTPUT fp32.
__global__ __launch_bounds__(256) void gemm_bias_out(
    const unsigned short* __restrict__ X,
    const float* __restrict__ W,
    const float* __restrict__ bias,
    float* __restrict__ out)
{
    __shared__ unsigned short lds_a[128 * 40];
    __shared__ unsigned short lds_b[128 * 40];

    const int tid  = threadIdx.x;
    const int lane = tid & 63;
    const int wave = tid >> 6;
    const int wm   = wave >> 1;
    const int wn   = wave & 1;
    const int quad = lane >> 4;
    const int col  = lane & 15;
    const int m0   = blockIdx.y * 128;
    const int n0   = blockIdx.x * 128;

    v4f acc[4][4];
#pragma unroll
    for (int i = 0; i < 4; i++)
#pragma unroll
        for (int j = 0; j < 4; j++)
#pragma unroll
            for (int r = 0; r < 4; r++) acc[i][j][r] = 0.0f;

    const int arow   = tid >> 1;
    const int achunk = (tid & 1) * 16;
    const int bk     = tid >> 4;
    const int bn     = (tid & 15) * 8;

    for (int k0 = 0; k0 < D_DIM; k0 += 32) {
        __syncthreads();
        {
            const unsigned short* src = X + (size_t)(m0 + arow) * D_DIM + k0 + achunk;
            v8s a0 = *(const v8s*)(src);
            v8s a1 = *(const v8s*)(src + 8);
            *(v8s*)(lds_a + arow * 40 + achunk)     = a0;
            *(v8s*)(lds_a + arow * 40 + achunk + 8) = a1;
        }
        {
            const float* s0 = W + (size_t)(k0 + bk) * D_DIM + n0 + bn;
            const float* s1 = W + (size_t)(k0 + bk + 16) * D_DIM + n0 + bn;
            float4 a0 = *(const float4*)(s0);
            float4 a1 = *(const float4*)(s0 + 4);
            float4 b0 = *(const float4*)(s1);
            float4 b1 = *(const float4*)(s1 + 4);
            float e0[8] = {a0.x,a0.y,a0.z,a0.w,a1.x,a1.y,a1.z,a1.w};
            float e1[8] = {b0.x,b0.y,b0.z,b0.w,b1.x,b1.y,b1.z,b1.w};
#pragma unroll
            for (int e = 0; e < 8; e++) {
                lds_b[(bn + e) * 40 + bk]      = f2bf(e0[e]);
                lds_b[(bn + e) * 40 + bk + 16] = f2bf(e1[e]);
            }
        }
        __syncthreads();

        v8s af[4], bf[4];
#pragma unroll
        for (int mt = 0; mt < 4; mt++)
            af[mt] = *(const v8s*)(lds_a + (wm * 64 + mt * 16 + col) * 40 + quad * 8);
#pragma unroll
        for (int nt = 0; nt < 4; nt++)
            bf[nt] = *(const v8s*)(lds_b + (wn * 64 + nt * 16 + col) * 40 + quad * 8);

#pragma unroll
        for (int mt = 0; mt < 4; mt++)
#pragma unroll
            for (int nt = 0; nt < 4; nt++)
                acc[mt][nt] = __builtin_amdgcn_mfma_f32_16x16x32_bf16(
                    af[mt], bf[nt], acc[mt][nt], 0, 0, 0);
    }

    float bvv[4];
#pragma unroll
    for (int nt = 0; nt < 4; nt++)
        bvv[nt] = bias[n0 + wn * 64 + nt * 16 + col];

#pragma unroll
    for (int mt = 0; mt < 4; mt++) {
#pragma unroll
        for (int nt = 0; nt < 4; nt++) {
#pragma unroll
            for (int r = 0; r < 4; r++) {
                int row = m0 + wm * 64 + mt * 16 + quad * 4 + r;
                int c   = n0 + wn * 64 + nt * 16 + col;
                out[(size_t)row * D_DIM + c] = acc[mt][nt][r] + bvv[nt];  // fp32 store
            }
        }
    }
}

// ---------------------------------------------------------------------------
// Flash attention, causal. Q/K/V bf16 in [B,S,D]; head h in cols [h*64,h*64+64).
// Grid: (S/64, B*H), block 256 (4 waves, 16 Q rows each).
// ---------------------------------------------------------------------------
__global__ __launch_bounds__(256) void flash_attn(
    const unsigned short* __restrict__ Q,
    const unsigned short* __restrict__ K,
    const unsigned short* __restrict__ V,
    unsigned short* __restrict__ O)
{
    __shared__ unsigned short lds_vt[64 * 72];      // V^T: [dk][key], stride 72
    __shared__ unsigned short lds_p[4 * 16 * 72];   // per-wave P: [qrow][key]

    const int tid  = threadIdx.x;
    const int lane = tid & 63;
    const int wave = tid >> 6;
    const int quad = lane >> 4;
    const int col  = lane & 15;

    const int qb = blockIdx.x * 64;
    const int bh = blockIdx.y;
    const int b  = bh >> 4;
    const int h  = bh & 15;
    const size_t base = (size_t)b * S_LEN * D_DIM + (size_t)h * DK;

    v8s qf[2];
#pragma unroll
    for (int c = 0; c < 2; c++)
        qf[c] = *(const v8s*)(Q + base + (size_t)(qb + wave * 16 + col) * D_DIM + c * 32 + quad * 8);

    float m_run[4], l_run[4];
    v4f acc_o[4];
#pragma unroll
    for (int r = 0; r < 4; r++) { m_run[r] = NEG_BIG; l_run[r] = 0.0f; }
#pragma unroll
    for (int nt = 0; nt < 4; nt++)
#pragma unroll
        for (int r = 0; r < 4; r++) acc_o[nt][r] = 0.0f;

    const float scale = 0.125f;
    const float l2e   = 1.44269504088896340736f;

    unsigned short* pw = lds_p + wave * 16 * 72;

    for (int kv0 = 0; kv0 <= qb; kv0 += 64) {
        __syncthreads();
        {
            const int keyr = tid >> 3;
            const int dkc  = (tid & 7) * 8;
#pragma unroll
            for (int p = 0; p < 2; p++) {
                int key = keyr + p * 32;
                v8s vv = *(const v8s*)(V + base + (size_t)(kv0 + key) * D_DIM + dkc);
#pragma unroll
                for (int e = 0; e < 8; e++)
                    lds_vt[(dkc + e) * 72 + key] = (unsigned short)vv[e];
            }
        }
        __syncthreads();

        v4f s[4];
#pragma unroll
        for (int nt = 0; nt < 4; nt++) {
#pragma unroll
            for (int r = 0; r < 4; r++) s[nt][r] = 0.0f;
#pragma unroll
            for (int c = 0; c < 2; c++) {
                v8s kf = *(const v8s*)(K + base + (size_t)(kv0 + nt * 16 + col) * D_DIM + c * 32 + quad * 8);
                s[nt] = __builtin_amdgcn_mfma_f32_16x16x32_bf16(qf[c], kf, s[nt], 0, 0, 0);
            }
        }

        const bool diag = (kv0 == qb);
#pragma unroll
        for (int nt = 0; nt < 4; nt++) {
#pragma unroll
            for (int r = 0; r < 4; r++) {
                float sv = s[nt][r] * scale;
                if (diag) {
                    int key = nt * 16 + col;
                    int qr  = wave * 16 + quad * 4 + r;
                    if (key > qr) sv = NEG_BIG;
                }
                s[nt][r] = sv;
            }
        }

        float mt_[4];
#pragma unroll
        for (int r = 0; r < 4; r++) {
            float mx = s[0][r];
#pragma unroll
            for (int nt = 1; nt < 4; nt++) mx = fmaxf(mx, s[nt][r]);
            mt_[r] = mx;
        }
#pragma unroll
        for (int off = 1; off < 16; off <<= 1)
#pragma unroll
            for (int r = 0; r < 4; r++) mt_[r] = fmaxf(mt_[r], __shfl_xor(mt_[r], off));

        float alpha[4];
#pragma unroll
        for (int r = 0; r < 4; r++) {
            float mnew = fmaxf(m_run[r], mt_[r]);
            alpha[r]   = exp2f((m_run[r] - mnew) * l2e);
            m_run[r]   = mnew;
        }

        float tsum[4] = {0.f, 0.f, 0.f, 0.f};
#pragma unroll
        for (int nt = 0; nt < 4; nt++) {
#pragma unroll
            for (int r = 0; r < 4; r++) {
                float p = exp2f((s[nt][r] - m_run[r]) * l2e);
                s[nt][r] = p;
                tsum[r] += p;
            }
        }
#pragma unroll
        for (int off = 1; off < 16; off <<= 1)
#pragma unroll
            for (int r = 0; r < 4; r++) tsum[r] += __shfl_xor(tsum[r], off);

#pragma unroll
        for (int r = 0; r < 4; r++) l_run[r] = l_run[r] * alpha[r] + tsum[r];
#pragma unroll
        for (int nt = 0; nt < 4; nt++)
#pragma unroll
            for (int r = 0; r < 4; r++) acc_o[nt][r] *= alpha[r];

#pragma unroll
        for (int nt = 0; nt < 4; nt++)
#pragma unroll
            for (int r = 0; r < 4; r++)
                pw[(quad * 4 + r) * 72 + nt * 16 + col] = f2bf(s[nt][r]);
        __syncthreads();

#pragma unroll
        for (int c = 0; c < 2; c++) {
            v8s af = *(const v8s*)(pw + col * 72 + c * 32 + quad * 8);
#pragma unroll
            for (int nt = 0; nt < 4; nt++) {
                v8s bfv = *(const v8s*)(lds_vt + (nt * 16 + col) * 72 + c * 32 + quad * 8);
                acc_o[nt] = __builtin_amdgcn_mfma_f32_16x16x32_bf16(af, bfv, acc_o[nt], 0, 0, 0);
            }
        }
    }

#pragma unroll
    for (int r = 0; r < 4; r++) l_run[r] = 1.0f / l_run[r];
#pragma unroll
    for (int nt = 0; nt < 4; nt++) {
#pragma unroll
        for (int r = 0; r < 4; r++) {
            size_t addr = base + (size_t)(qb + wave * 16 + quad * 4 + r) * D_DIM + nt * 16 + col;
            O[addr] = f2bf(acc_o[nt][r] * l_run[r]);
        }
    }
}

// ---------------------------------------------------------------------------
extern "C" void kernel_launch(void* const* d_in, const int* in_sizes, int n_in,
                              void* d_out, int out_size, void* d_ws, size_t ws_size,
                              hipStream_t stream) {
    const float* q  = (const float*)d_in[0];
    const float* k  = (const float*)d_in[1];
    const float* v  = (const float*)d_in[2];
    // d_in[3] = causal mask — known analytically, unused
    const float* Wq = (const float*)d_in[4];
    const float* bq = (const float*)d_in[5];
    const float* Wk = (const float*)d_in[6];
    const float* bk = (const float*)d_in[7];
    const float* Wv = (const float*)d_in[8];
    const float* bv = (const float*)d_in[9];
    const float* Wo = (const float*)d_in[10];
    const float* bo = (const float*)d_in[11];
    float* out = (float*)d_out;  // fp32 output per reference dtype

    unsigned short* ws = (unsigned short*)d_ws;
    const size_t TENS = (size_t)M_ROWS * D_DIM;  // 4M elements (8MB bf16 each)
    unsigned short* Qw = ws;
    unsigned short* Kw = ws + TENS;
    unsigned short* Vw = ws + 2 * TENS;
    unsigned short* Aw = ws + 3 * TENS;

    dim3 gg(D_DIM / 128, M_ROWS / 128);  // (8, 32)
    gemm_bias_f32<<<gg, 256, 0, stream>>>(q, Wq, bq, Qw);
    gemm_bias_f32<<<gg, 256, 0, stream>>>(k, Wk, bk, Kw);
    gemm_bias_f32<<<gg, 256, 0, stream>>>(v, Wv, bv, Vw);
    flash_attn<<<dim3(S_LEN / 64, 2 * NHEAD), 256, 0, stream>>>(Qw, Kw, Vw, Aw);
    gemm_bias_out<<<gg, 256, 0, stream>>>(Aw, Wo, bo, out);
}

// Round 5
// 507.354 us; speedup vs baseline: 1.1710x; 1.1710x over previous
//
#include <hip/hip_runtime.h>

// MultiHeadAttention: B=2, S=2048, D=1024, H=16, DK=64, causal.
// Inputs fp32, output fp32, intermediates bf16.
// R4: restructure for occupancy + barrier removal:
//   transpose_w:  W fp32 [k][n] -> Wt bf16 [n][k]  (once, 4 weights via grid.z)
//   gemm_qkv:     fused Q/K/V proj (grid.z), 64x128 tiles, A via LDS, B direct
//                 from Wt (global, contiguous). Q/K out packed [B,H,S,DK];
//                 V out transposed Vt [B,H,DK,S].
//   flash2:       barrier-free flash attention (per-wave independence),
//                 K/Vt fragments direct from global, reversed qtile order.
//   gemm_out:     final proj from packed attn-out, fp32 stores.
// ws: Wt 8MB + Qp 8 + Kp 8 + Vt 8 + Ap 8 = 40 MB.

typedef short v8s __attribute__((ext_vector_type(8)));   // 8 x bf16
typedef float v4f __attribute__((ext_vector_type(4)));   // MFMA acc

#define S_LEN 2048
#define D_DIM 1024
#define NHEAD 16
#define DK 64
#define M_ROWS 4096   // B*S
#define NEG_BIG -30000.0f

__device__ inline unsigned short f2bf(float f) {
    unsigned x;
    __builtin_memcpy(&x, &f, 4);
    unsigned r = x + 0x7fffu + ((x >> 16) & 1u);  // RNE
    return (unsigned short)(r >> 16);
}

// ---------------------------------------------------------------------------
// Weight transpose+cast: W fp32 [1024 k][1024 n] -> Wt bf16 [1024 n][1024 k].
// Grid (16,16,4), 256 threads. z selects which weight.
// ---------------------------------------------------------------------------
__global__ __launch_bounds__(256) void transpose_w(
    const float* __restrict__ W0, const float* __restrict__ W1,
    const float* __restrict__ W2, const float* __restrict__ W3,
    unsigned short* __restrict__ Wt)   // 4 x [1024][1024] bf16, contiguous
{
    const int z = blockIdx.z;
    const float* W = (z == 0) ? W0 : (z == 1) ? W1 : (z == 2) ? W2 : W3;
    unsigned short* dst = Wt + (size_t)z * D_DIM * D_DIM;

    __shared__ unsigned short t[64][72];
    const int n0 = blockIdx.x * 64, k0 = blockIdx.y * 64;
    const int tid = threadIdx.x;
    const int lr = tid >> 4;          // 0..15
    const int lc = (tid & 15) * 4;    // 0..60

#pragma unroll
    for (int kk = 0; kk < 64; kk += 16) {
        float4 f = *(const float4*)(W + (size_t)(k0 + kk + lr) * D_DIM + n0 + lc);
        t[lc + 0][kk + lr] = f2bf(f.x);
        t[lc + 1][kk + lr] = f2bf(f.y);
        t[lc + 2][kk + lr] = f2bf(f.z);
        t[lc + 3][kk + lr] = f2bf(f.w);
    }
    __syncthreads();
    const int wr = tid >> 2;          // 0..63 (n within tile)
    const int wc = (tid & 3) * 16;    // 0,16,32,48
    v8s o0, o1;
#pragma unroll
    for (int e = 0; e < 8; e++) { o0[e] = t[wr][wc + e]; o1[e] = t[wr][wc + 8 + e]; }
    *(v8s*)(dst + (size_t)(n0 + wr) * D_DIM + k0 + wc)     = o0;
    *(v8s*)(dst + (size_t)(n0 + wr) * D_DIM + k0 + wc + 8) = o1;
}

// ---------------------------------------------------------------------------
// Fused QKV projection. Grid (8 ncol, 64 mrow, 3), 256 threads (4 waves).
// Tile 64(m) x 128(n), BK=32. Wave: 32(m) x 64(n) = 2x4 mfma subtiles.
// z=0: Q -> packed Qp[B,H,S,DK]; z=1: K -> Kp; z=2: V -> Vt[B,H,DK,S].
// ---------------------------------------------------------------------------
__global__ __launch_bounds__(256) void gemm_qkv(
    const float* __restrict__ q, const float* __restrict__ k,
    const float* __restrict__ v,
    const unsigned short* __restrict__ Wt,   // 4 weights contiguous; use z
    const float* __restrict__ bq, const float* __restrict__ bk,
    const float* __restrict__ bv,
    unsigned short* __restrict__ Qp, unsigned short* __restrict__ Kp,
    unsigned short* __restrict__ Vt)
{
    const int z = blockIdx.z;
    const float* X = (z == 0) ? q : (z == 1) ? k : v;
    const unsigned short* W = Wt + (size_t)z * D_DIM * D_DIM;
    const float* bias = (z == 0) ? bq : (z == 1) ? bk : bv;

    __shared__ unsigned short lds_a[64 * 40];   // [m][k] bf16, stride 40

    const int tid  = threadIdx.x;
    const int lane = tid & 63;
    const int wave = tid >> 6;
    const int wm   = wave >> 1;      // 0..1
    const int wn   = wave & 1;       // 0..1
    const int quad = lane >> 4;
    const int col  = lane & 15;
    const int m0   = blockIdx.y * 64;
    const int n0   = blockIdx.x * 128;

    v4f acc[2][4];
#pragma unroll
    for (int i = 0; i < 2; i++)
#pragma unroll
        for (int j = 0; j < 4; j++)
#pragma unroll
            for (int r = 0; r < 4; r++) acc[i][j][r] = 0.0f;

    const int arow = tid >> 2;          // 0..63
    const int achk = (tid & 3) * 8;     // 0..24

    for (int k0 = 0; k0 < D_DIM; k0 += 32) {
        __syncthreads();
        {
            const float* src = X + (size_t)(m0 + arow) * D_DIM + k0 + achk;
            float4 f0 = *(const float4*)(src);
            float4 f1 = *(const float4*)(src + 4);
            v8s p;
            p[0]=(short)f2bf(f0.x); p[1]=(short)f2bf(f0.y); p[2]=(short)f2bf(f0.z); p[3]=(short)f2bf(f0.w);
            p[4]=(short)f2bf(f1.x); p[5]=(short)f2bf(f1.y); p[6]=(short)f2bf(f1.z); p[7]=(short)f2bf(f1.w);
            *(v8s*)(lds_a + arow * 40 + achk) = p;
        }
        __syncthreads();

        v8s af[2], bf[4];
#pragma unroll
        for (int mt = 0; mt < 2; mt++)
            af[mt] = *(const v8s*)(lds_a + (wm * 32 + mt * 16 + col) * 40 + quad * 8);
#pragma unroll
        for (int nt = 0; nt < 4; nt++)
            bf[nt] = *(const v8s*)(W + (size_t)(n0 + wn * 64 + nt * 16 + col) * D_DIM + k0 + quad * 8);

#pragma unroll
        for (int mt = 0; mt < 2; mt++)
#pragma unroll
            for (int nt = 0; nt < 4; nt++)
                acc[mt][nt] = __builtin_amdgcn_mfma_f32_16x16x32_bf16(
                    af[mt], bf[nt], acc[mt][nt], 0, 0, 0);
    }

    int   nn[4];
    float bvv[4];
#pragma unroll
    for (int nt = 0; nt < 4; nt++) {
        nn[nt]  = n0 + wn * 64 + nt * 16 + col;
        bvv[nt] = bias[nn[nt]];
    }

    if (z < 2) {
        unsigned short* out = (z == 0) ? Qp : Kp;
#pragma unroll
        for (int mt = 0; mt < 2; mt++) {
#pragma unroll
            for (int nt = 0; nt < 4; nt++) {
                const int h  = nn[nt] >> 6;
                const int dk = nn[nt] & 63;
#pragma unroll
                for (int r = 0; r < 4; r++) {
                    int row = m0 + wm * 32 + mt * 16 + quad * 4 + r;
                    int b   = row >> 11, t = row & 2047;
                    out[(((size_t)(b * NHEAD + h) * S_LEN) + t) * DK + dk] =
                        f2bf(acc[mt][nt][r] + bvv[nt]);
                }
            }
        }
    } else {
        // V -> Vt [B,H,DK,S]; pack 4 consecutive tokens per store (8B).
        typedef short v4ss __attribute__((ext_vector_type(4)));
#pragma unroll
        for (int mt = 0; mt < 2; mt++) {
#pragma unroll
            for (int nt = 0; nt < 4; nt++) {
                const int h  = nn[nt] >> 6;
                const int dk = nn[nt] & 63;
                int row = m0 + wm * 32 + mt * 16 + quad * 4;  // r=0 token
                int b   = row >> 11, t = row & 2047;
                v4ss pk;
#pragma unroll
                for (int r = 0; r < 4; r++) pk[r] = (short)f2bf(acc[mt][nt][r] + bvv[nt]);
                *(v4ss*)(Vt + ((size_t)(b * NHEAD + h) * DK + dk) * S_LEN + t) = pk;
            }
        }
    }
}

// ---------------------------------------------------------------------------
// Flash attention v2 — barrier-free. Grid (32 qtiles reversed, 32 bh), 256 thr.
// Qp/Kp packed [BH][S][DK]; Vt [BH][DK][S]; out Op packed [BH][S][DK].
// Each wave owns 16 Q rows; P roundtrips through per-wave LDS (stride 88).
// ---------------------------------------------------------------------------
__global__ __launch_bounds__(256) void flash2(
    const unsigned short* __restrict__ Qp,
    const unsigned short* __restrict__ Kp,
    const unsigned short* __restrict__ Vt,
    unsigned short* __restrict__ Op)
{
    __shared__ unsigned short lds_p[4 * 16 * 88];

    const int tid  = threadIdx.x;
    const int lane = tid & 63;
    const int wave = tid >> 6;
    const int quad = lane >> 4;
    const int col  = lane & 15;

    const int qb = (int)(gridDim.x - 1 - blockIdx.x) * 64;   // long blocks first
    const int bh = blockIdx.y;
    const unsigned short* Qh = Qp + (size_t)bh * S_LEN * DK;
    const unsigned short* Kh = Kp + (size_t)bh * S_LEN * DK;
    const unsigned short* Vh = Vt + (size_t)bh * DK * S_LEN;
    unsigned short* pw = lds_p + wave * 16 * 88;

    v8s qf[2];
#pragma unroll
    for (int c = 0; c < 2; c++)
        qf[c] = *(const v8s*)(Qh + (size_t)(qb + wave * 16 + col) * DK + c * 32 + quad * 8);

    float m_run[4], l_run[4];
    v4f acc_o[4];
#pragma unroll
    for (int r = 0; r < 4; r++) { m_run[r] = NEG_BIG; l_run[r] = 0.0f; }
#pragma unroll
    for (int nt = 0; nt < 4; nt++)
#pragma unroll
        for (int r = 0; r < 4; r++) acc_o[nt][r] = 0.0f;

    const float scale = 0.125f;
    const float l2e   = 1.44269504088896340736f;

    for (int kv0 = 0; kv0 <= qb; kv0 += 64) {
        // S = Q @ K^T (K B-fragments direct from packed global)
        v4f s[4];
#pragma unroll
        for (int nt = 0; nt < 4; nt++) {
#pragma unroll
            for (int r = 0; r < 4; r++) s[nt][r] = 0.0f;
#pragma unroll
            for (int c = 0; c < 2; c++) {
                v8s kf = *(const v8s*)(Kh + (size_t)(kv0 + nt * 16 + col) * DK + c * 32 + quad * 8);
                s[nt] = __builtin_amdgcn_mfma_f32_16x16x32_bf16(qf[c], kf, s[nt], 0, 0, 0);
            }
        }

        const bool diag = (kv0 == qb);
#pragma unroll
        for (int nt = 0; nt < 4; nt++) {
#pragma unroll
            for (int r = 0; r < 4; r++) {
                float sv = s[nt][r] * scale;
                if (diag) {
                    int key = nt * 16 + col;
                    int qr  = wave * 16 + quad * 4 + r;
                    if (key > qr) sv = NEG_BIG;
                }
                s[nt][r] = sv;
            }
        }

        // online softmax over the 16 lanes of each quad-row
        float mt_[4];
#pragma unroll
        for (int r = 0; r < 4; r++) {
            float mx = s[0][r];
#pragma unroll
            for (int nt = 1; nt < 4; nt++) mx = fmaxf(mx, s[nt][r]);
            mt_[r] = mx;
        }
#pragma unroll
        for (int off = 1; off < 16; off <<= 1)
#pragma unroll
            for (int r = 0; r < 4; r++) mt_[r] = fmaxf(mt_[r], __shfl_xor(mt_[r], off));

        float alpha[4];
#pragma unroll
        for (int r = 0; r < 4; r++) {
            float mnew = fmaxf(m_run[r], mt_[r]);
            alpha[r]   = exp2f((m_run[r] - mnew) * l2e);
            m_run[r]   = mnew;
        }

        float tsum[4] = {0.f, 0.f, 0.f, 0.f};
#pragma unroll
        for (int nt = 0; nt < 4; nt++) {
#pragma unroll
            for (int r = 0; r < 4; r++) {
                float p = exp2f((s[nt][r] - m_run[r]) * l2e);
                s[nt][r] = p;
                tsum[r] += p;
            }
        }
#pragma unroll
        for (int off = 1; off < 16; off <<= 1)
#pragma unroll
            for (int r = 0; r < 4; r++) tsum[r] += __shfl_xor(tsum[r], off);

#pragma unroll
        for (int r = 0; r < 4; r++) l_run[r] = l_run[r] * alpha[r] + tsum[r];
#pragma unroll
        for (int nt = 0; nt < 4; nt++)
#pragma unroll
            for (int r = 0; r < 4; r++) acc_o[nt][r] *= alpha[r];

        // P: C-layout -> per-wave LDS [qrow][key] (stride 88: 16B-aligned rows)
#pragma unroll
        for (int nt = 0; nt < 4; nt++)
#pragma unroll
            for (int r = 0; r < 4; r++)
                pw[(quad * 4 + r) * 88 + nt * 16 + col] = f2bf(s[nt][r]);

        // O += P @ V  (V^T B-fragments direct from global Vt)
#pragma unroll
        for (int c = 0; c < 2; c++) {
            v8s af = *(const v8s*)(pw + col * 88 + c * 32 + quad * 8);
#pragma unroll
            for (int nt = 0; nt < 4; nt++) {
                v8s vf = *(const v8s*)(Vh + (size_t)(nt * 16 + col) * S_LEN + kv0 + c * 32 + quad * 8);
                acc_o[nt] = __builtin_amdgcn_mfma_f32_16x16x32_bf16(af, vf, acc_o[nt], 0, 0, 0);
            }
        }
    }

    // epilogue: O /= l, store packed [BH][S][DK]
#pragma unroll
    for (int r = 0; r < 4; r++) l_run[r] = 1.0f / l_run[r];
#pragma unroll
    for (int nt = 0; nt < 4; nt++) {
#pragma unroll
        for (int r = 0; r < 4; r++) {
            size_t addr = ((size_t)bh * S_LEN + qb + wave * 16 + quad * 4 + r) * DK + nt * 16 + col;
            Op[addr] = f2bf(acc_o[nt][r] * l_run[r]);
        }
    }
}

// ---------------------------------------------------------------------------
// Final projection: out[M][1024] fp32 = Ap(packed bf16) @ Wo + bo.
// Grid (8, 64), 256 threads, 64x128 tiles.
// ---------------------------------------------------------------------------
__global__ __launch_bounds__(256) void gemm_out(
    const unsigned short* __restrict__ Ap,   // packed [BH][S][DK]
    const unsigned short* __restrict__ Wot,  // bf16 [n][k]
    const float* __restrict__ bo,
    float* __restrict__ out)
{
    __shared__ unsigned short lds_a[64 * 40];

    const int tid  = threadIdx.x;
    const int lane = tid & 63;
    const int wave = tid >> 6;
    const int wm   = wave >> 1;
    const int wn   = wave & 1;
    const int quad = lane >> 4;
    const int col  = lane & 15;
    const int m0   = blockIdx.y * 64;
    const int n0   = blockIdx.x * 128;

    v4f acc[2][4];
#pragma unroll
    for (int i = 0; i < 2; i++)
#pragma unroll
        for (int j = 0; j < 4; j++)
#pragma unroll
            for (int r = 0; r < 4; r++) acc[i][j][r] = 0.0f;

    const int arow = tid >> 2;
    const int achk = (tid & 3) * 8;

    for (int k0 = 0; k0 < D_DIM; k0 += 32) {
        __syncthreads();
        {
            int token = m0 + arow;
            int b = token >> 11, t = token & 2047;
            int h = k0 >> 6;
            int dk = (k0 & 63) + achk;
            v8s a = *(const v8s*)(Ap + ((size_t)(b * NHEAD + h) * S_LEN + t) * DK + dk);
            *(v8s*)(lds_a + arow * 40 + achk) = a;
        }
        __syncthreads();

        v8s af[2], bf[4];
#pragma unroll
        for (int mt = 0; mt < 2; mt++)
            af[mt] = *(const v8s*)(lds_a + (wm * 32 + mt * 16 + col) * 40 + quad * 8);
#pragma unroll
        for (int nt = 0; nt < 4; nt++)
            bf[nt] = *(const v8s*)(Wot + (size_t)(n0 + wn * 64 + nt * 16 + col) * D_DIM + k0 + quad * 8);

#pragma unroll
        for (int mt = 0; mt < 2; mt++)
#pragma unroll
            for (int nt = 0; nt < 4; nt++)
                acc[mt][nt] = __builtin_amdgcn_mfma_f32_16x16x32_bf16(
                    af[mt], bf[nt], acc[mt][nt], 0, 0, 0);
    }

    float bvv[4];
    int   nn[4];
#pragma unroll
    for (int nt = 0; nt < 4; nt++) {
        nn[nt]  = n0 + wn * 64 + nt * 16 + col;
        bvv[nt] = bo[nn[nt]];
    }

#pragma unroll
    for (int mt = 0; mt < 2; mt++) {
#pragma unroll
        for (int nt = 0; nt < 4; nt++) {
#pragma unroll
            for (int r = 0; r < 4; r++) {
                int row = m0 + wm * 32 + mt * 16 + quad * 4 + r;
                out[(size_t)row * D_DIM + nn[nt]] = acc[mt][nt][r] + bvv[nt];
            }
        }
    }
}

// ---------------------------------------------------------------------------
extern "C" void kernel_launch(void* const* d_in, const int* in_sizes, int n_in,
                              void* d_out, int out_size, void* d_ws, size_t ws_size,
                              hipStream_t stream) {
    const float* q  = (const float*)d_in[0];
    const float* k  = (const float*)d_in[1];
    const float* v  = (const float*)d_in[2];
    // d_in[3] = causal mask — analytic, unused
    const float* Wq = (const float*)d_in[4];
    const float* bq = (const float*)d_in[5];
    const float* Wk = (const float*)d_in[6];
    const float* bk = (const float*)d_in[7];
    const float* Wv = (const float*)d_in[8];
    const float* bv = (const float*)d_in[9];
    const float* Wo = (const float*)d_in[10];
    const float* bo = (const float*)d_in[11];
    float* out = (float*)d_out;

    unsigned short* ws = (unsigned short*)d_ws;
    const size_t WT   = (size_t)D_DIM * D_DIM;       // 1M elems per weight
    const size_t TENS = (size_t)M_ROWS * D_DIM;      // 4M elems
    unsigned short* Wt = ws;                          // 4 weights: 8 MB
    unsigned short* Qp = ws + 4 * WT;                 // 8 MB
    unsigned short* Kp = Qp + TENS;                   // 8 MB
    unsigned short* Vt = Kp + TENS;                   // 8 MB
    unsigned short* Ap = Vt + TENS;                   // 8 MB  (total 40 MB)

    transpose_w<<<dim3(16, 16, 4), 256, 0, stream>>>(Wq, Wk, Wv, Wo, Wt);
    gemm_qkv<<<dim3(8, 64, 3), 256, 0, stream>>>(q, k, v, Wt, bq, bk, bv, Qp, Kp, Vt);
    flash2<<<dim3(S_LEN / 64, 2 * NHEAD), 256, 0, stream>>>(Qp, Kp, Vt, Ap);
    gemm_out<<<dim3(8, 64), 256, 0, stream>>>(Ap, Wt + 3 * WT, bo, out);
}

// Round 6
// 488.728 us; speedup vs baseline: 1.2157x; 1.0381x over previous
//
#include <hip/hip_runtime.h>

// MultiHeadAttention: B=2, S=2048, D=1024, H=16, DK=64, causal.
// Inputs fp32, output fp32, intermediates bf16.
// R6: latency attack.
//   flash3:   single-wave (64-thr) blocks, 16 Q rows each, grid (128,32)=4096
//             blocks -> 16 wg/CU, fine-grained balance, longest first, 0 barriers.
//   gemm_qkv: 128x128 tiles (16 MFMA/step/wave), A-LDS staged w/ reg prefetch,
//             B direct from Wt w/ reg prefetch.
//   gemm_out: 64x128 tiles + same prefetch.
// ws: Wt 8MB + Qp 8 + Kp 8 + Vt 8 + Ap 8 = 40 MB.

typedef short v8s  __attribute__((ext_vector_type(8)));
typedef short v4ss __attribute__((ext_vector_type(4)));
typedef float v4f  __attribute__((ext_vector_type(4)));

#define S_LEN 2048
#define D_DIM 1024
#define NHEAD 16
#define DK 64
#define M_ROWS 4096
#define NEG_BIG -30000.0f

__device__ inline unsigned short f2bf(float f) {
    unsigned x;
    __builtin_memcpy(&x, &f, 4);
    unsigned r = x + 0x7fffu + ((x >> 16) & 1u);  // RNE
    return (unsigned short)(r >> 16);
}

// ---------------------------------------------------------------------------
// Weight transpose+cast: W fp32 [k][n] -> Wt bf16 [n][k]. Grid (16,16,4).
// ---------------------------------------------------------------------------
__global__ __launch_bounds__(256) void transpose_w(
    const float* __restrict__ W0, const float* __restrict__ W1,
    const float* __restrict__ W2, const float* __restrict__ W3,
    unsigned short* __restrict__ Wt)
{
    const int z = blockIdx.z;
    const float* W = (z == 0) ? W0 : (z == 1) ? W1 : (z == 2) ? W2 : W3;
    unsigned short* dst = Wt + (size_t)z * D_DIM * D_DIM;

    __shared__ unsigned short t[64][72];
    const int n0 = blockIdx.x * 64, k0 = blockIdx.y * 64;
    const int tid = threadIdx.x;
    const int lr = tid >> 4;
    const int lc = (tid & 15) * 4;

#pragma unroll
    for (int kk = 0; kk < 64; kk += 16) {
        float4 f = *(const float4*)(W + (size_t)(k0 + kk + lr) * D_DIM + n0 + lc);
        t[lc + 0][kk + lr] = f2bf(f.x);
        t[lc + 1][kk + lr] = f2bf(f.y);
        t[lc + 2][kk + lr] = f2bf(f.z);
        t[lc + 3][kk + lr] = f2bf(f.w);
    }
    __syncthreads();
    const int wr = tid >> 2;
    const int wc = (tid & 3) * 16;
    v8s o0, o1;
#pragma unroll
    for (int e = 0; e < 8; e++) { o0[e] = t[wr][wc + e]; o1[e] = t[wr][wc + 8 + e]; }
    *(v8s*)(dst + (size_t)(n0 + wr) * D_DIM + k0 + wc)     = o0;
    *(v8s*)(dst + (size_t)(n0 + wr) * D_DIM + k0 + wc + 8) = o1;
}

// ---------------------------------------------------------------------------
// Fused QKV projection. Grid (8, 32, 3), 256 thr. Tile 128x128, BK=32.
// Wave: 64x64 (4x4 subtiles). A via LDS (fp32->bf16), B direct from Wt.
// Register prefetch of next-step A and B. z=0:Qp z=1:Kp z=2:Vt.
// ---------------------------------------------------------------------------
__global__ __launch_bounds__(256) void gemm_qkv(
    const float* __restrict__ q, const float* __restrict__ k,
    const float* __restrict__ v,
    const unsigned short* __restrict__ Wt,
    const float* __restrict__ bq, const float* __restrict__ bk,
    const float* __restrict__ bv,
    unsigned short* __restrict__ Qp, unsigned short* __restrict__ Kp,
    unsigned short* __restrict__ Vt)
{
    const int z = blockIdx.z;
    const float* X = (z == 0) ? q : (z == 1) ? k : v;
    const unsigned short* W = Wt + (size_t)z * D_DIM * D_DIM;
    const float* bias = (z == 0) ? bq : (z == 1) ? bk : bv;

    __shared__ unsigned short lds_a[128 * 40];

    const int tid  = threadIdx.x;
    const int lane = tid & 63;
    const int wave = tid >> 6;
    const int wm   = wave >> 1;
    const int wn   = wave & 1;
    const int quad = lane >> 4;
    const int col  = lane & 15;
    const int m0   = blockIdx.y * 128;
    const int n0   = blockIdx.x * 128;

    v4f acc[4][4];
#pragma unroll
    for (int i = 0; i < 4; i++)
#pragma unroll
        for (int j = 0; j < 4; j++)
#pragma unroll
            for (int r = 0; r < 4; r++) acc[i][j][r] = 0.0f;

    const int arow = tid >> 1;          // 0..127
    const int achk = (tid & 1) * 16;    // 0 / 16
    const float* asrc = X + (size_t)(m0 + arow) * D_DIM + achk;
    const unsigned short* bsrc[4];
#pragma unroll
    for (int nt = 0; nt < 4; nt++)
        bsrc[nt] = W + (size_t)(n0 + wn * 64 + nt * 16 + col) * D_DIM + quad * 8;

    // prefetch k0=0
    float4 ar[4];
#pragma unroll
    for (int i = 0; i < 4; i++) ar[i] = *(const float4*)(asrc + i * 4);
    v8s bc[4];
#pragma unroll
    for (int nt = 0; nt < 4; nt++) bc[nt] = *(const v8s*)(bsrc[nt]);

    for (int k0 = 0; k0 < D_DIM; k0 += 32) {
        __syncthreads();
        {
            v8s p0, p1;
            p0[0]=(short)f2bf(ar[0].x); p0[1]=(short)f2bf(ar[0].y); p0[2]=(short)f2bf(ar[0].z); p0[3]=(short)f2bf(ar[0].w);
            p0[4]=(short)f2bf(ar[1].x); p0[5]=(short)f2bf(ar[1].y); p0[6]=(short)f2bf(ar[1].z); p0[7]=(short)f2bf(ar[1].w);
            p1[0]=(short)f2bf(ar[2].x); p1[1]=(short)f2bf(ar[2].y); p1[2]=(short)f2bf(ar[2].z); p1[3]=(short)f2bf(ar[2].w);
            p1[4]=(short)f2bf(ar[3].x); p1[5]=(short)f2bf(ar[3].y); p1[6]=(short)f2bf(ar[3].z); p1[7]=(short)f2bf(ar[3].w);
            *(v8s*)(lds_a + arow * 40 + achk)     = p0;
            *(v8s*)(lds_a + arow * 40 + achk + 8) = p1;
        }
        __syncthreads();

        // prefetch next step (clamped on last iter; redundant loads, unused)
        const int kn = (k0 + 32 < D_DIM) ? (k0 + 32) : k0;
        float4 arn[4];
#pragma unroll
        for (int i = 0; i < 4; i++) arn[i] = *(const float4*)(asrc + kn + i * 4);
        v8s bn[4];
#pragma unroll
        for (int nt = 0; nt < 4; nt++) bn[nt] = *(const v8s*)(bsrc[nt] + kn);

        v8s af[4];
#pragma unroll
        for (int mt = 0; mt < 4; mt++)
            af[mt] = *(const v8s*)(lds_a + (wm * 64 + mt * 16 + col) * 40 + quad * 8);

#pragma unroll
        for (int mt = 0; mt < 4; mt++)
#pragma unroll
            for (int nt = 0; nt < 4; nt++)
                acc[mt][nt] = __builtin_amdgcn_mfma_f32_16x16x32_bf16(
                    af[mt], bc[nt], acc[mt][nt], 0, 0, 0);

#pragma unroll
        for (int i = 0; i < 4; i++) ar[i] = arn[i];
#pragma unroll
        for (int nt = 0; nt < 4; nt++) bc[nt] = bn[nt];
    }

    int   nn[4];
    float bvv[4];
#pragma unroll
    for (int nt = 0; nt < 4; nt++) {
        nn[nt]  = n0 + wn * 64 + nt * 16 + col;
        bvv[nt] = bias[nn[nt]];
    }

    if (z < 2) {
        unsigned short* out = (z == 0) ? Qp : Kp;
#pragma unroll
        for (int mt = 0; mt < 4; mt++) {
#pragma unroll
            for (int nt = 0; nt < 4; nt++) {
                const int h  = nn[nt] >> 6;
                const int dk = nn[nt] & 63;
#pragma unroll
                for (int r = 0; r < 4; r++) {
                    int row = m0 + wm * 64 + mt * 16 + quad * 4 + r;
                    int b   = row >> 11, t = row & 2047;
                    out[(((size_t)(b * NHEAD + h) * S_LEN) + t) * DK + dk] =
                        f2bf(acc[mt][nt][r] + bvv[nt]);
                }
            }
        }
    } else {
#pragma unroll
        for (int mt = 0; mt < 4; mt++) {
#pragma unroll
            for (int nt = 0; nt < 4; nt++) {
                const int h  = nn[nt] >> 6;
                const int dk = nn[nt] & 63;
                int row = m0 + wm * 64 + mt * 16 + quad * 4;
                int b   = row >> 11, t = row & 2047;
                v4ss pk;
#pragma unroll
                for (int r = 0; r < 4; r++) pk[r] = (short)f2bf(acc[mt][nt][r] + bvv[nt]);
                *(v4ss*)(Vt + ((size_t)(b * NHEAD + h) * DK + dk) * S_LEN + t) = pk;
            }
        }
    }
}

// ---------------------------------------------------------------------------
// Flash attention v3 — single-wave blocks. Grid (128, 32), 64 threads.
// Block handles 16 Q rows (reversed order: longest first). No barriers.
// ---------------------------------------------------------------------------
__global__ __launch_bounds__(64) void flash3(
    const unsigned short* __restrict__ Qp,
    const unsigned short* __restrict__ Kp,
    const unsigned short* __restrict__ Vt,
    unsigned short* __restrict__ Op)
{
    __shared__ unsigned short pw[16 * 72];   // per-wave P: [qrow][key]

    const int lane = threadIdx.x;
    const int quad = lane >> 4;
    const int col  = lane & 15;

    const int q16 = (int)(gridDim.x - 1 - blockIdx.x);   // longest first
    const int r0  = q16 * 16;
    const int bh  = blockIdx.y;
    const unsigned short* Qh = Qp + (size_t)bh * S_LEN * DK;
    const unsigned short* Kh = Kp + (size_t)bh * S_LEN * DK;
    const unsigned short* Vh = Vt + (size_t)bh * DK * S_LEN;

    v8s qf[2];
#pragma unroll
    for (int c = 0; c < 2; c++)
        qf[c] = *(const v8s*)(Qh + (size_t)(r0 + col) * DK + c * 32 + quad * 8);

    float m_run[4], l_run[4];
    v4f acc_o[4];
#pragma unroll
    for (int r = 0; r < 4; r++) { m_run[r] = NEG_BIG; l_run[r] = 0.0f; }
#pragma unroll
    for (int nt = 0; nt < 4; nt++)
#pragma unroll
        for (int r = 0; r < 4; r++) acc_o[nt][r] = 0.0f;

    const float scale = 0.125f;
    const float l2e   = 1.44269504088896340736f;

    const int nsteps = q16 / 4 + 1;
    for (int step = 0; step < nsteps; step++) {
        const int kv0 = step * 64;

        v4f s[4];
#pragma unroll
        for (int nt = 0; nt < 4; nt++) {
#pragma unroll
            for (int r = 0; r < 4; r++) s[nt][r] = 0.0f;
#pragma unroll
            for (int c = 0; c < 2; c++) {
                v8s kf = *(const v8s*)(Kh + (size_t)(kv0 + nt * 16 + col) * DK + c * 32 + quad * 8);
                s[nt] = __builtin_amdgcn_mfma_f32_16x16x32_bf16(qf[c], kf, s[nt], 0, 0, 0);
            }
        }

        const bool diag = (kv0 + 64 > r0);
#pragma unroll
        for (int nt = 0; nt < 4; nt++) {
#pragma unroll
            for (int r = 0; r < 4; r++) {
                float sv = s[nt][r] * scale;
                if (diag) {
                    int key = kv0 + nt * 16 + col;
                    int qr  = r0 + quad * 4 + r;
                    if (key > qr) sv = NEG_BIG;
                }
                s[nt][r] = sv;
            }
        }

        float mt_[4];
#pragma unroll
        for (int r = 0; r < 4; r++) {
            float mx = s[0][r];
#pragma unroll
            for (int nt = 1; nt < 4; nt++) mx = fmaxf(mx, s[nt][r]);
            mt_[r] = mx;
        }
#pragma unroll
        for (int off = 1; off < 16; off <<= 1)
#pragma unroll
            for (int r = 0; r < 4; r++) mt_[r] = fmaxf(mt_[r], __shfl_xor(mt_[r], off));

        float alpha[4];
#pragma unroll
        for (int r = 0; r < 4; r++) {
            float mnew = fmaxf(m_run[r], mt_[r]);
            alpha[r]   = exp2f((m_run[r] - mnew) * l2e);
            m_run[r]   = mnew;
        }

        float tsum[4] = {0.f, 0.f, 0.f, 0.f};
#pragma unroll
        for (int nt = 0; nt < 4; nt++) {
#pragma unroll
            for (int r = 0; r < 4; r++) {
                float p = exp2f((s[nt][r] - m_run[r]) * l2e);
                s[nt][r] = p;
                tsum[r] += p;
            }
        }
#pragma unroll
        for (int off = 1; off < 16; off <<= 1)
#pragma unroll
            for (int r = 0; r < 4; r++) tsum[r] += __shfl_xor(tsum[r], off);

#pragma unroll
        for (int r = 0; r < 4; r++) l_run[r] = l_run[r] * alpha[r] + tsum[r];
#pragma unroll
        for (int nt = 0; nt < 4; nt++)
#pragma unroll
            for (int r = 0; r < 4; r++) acc_o[nt][r] *= alpha[r];

        // P: C-layout -> per-wave LDS -> A-layout (wave-internal, no barrier)
#pragma unroll
        for (int nt = 0; nt < 4; nt++)
#pragma unroll
            for (int r = 0; r < 4; r++)
                pw[(quad * 4 + r) * 72 + nt * 16 + col] = f2bf(s[nt][r]);

#pragma unroll
        for (int c = 0; c < 2; c++) {
            v8s af = *(const v8s*)(pw + col * 72 + c * 32 + quad * 8);
#pragma unroll
            for (int nt = 0; nt < 4; nt++) {
                v8s vf = *(const v8s*)(Vh + (size_t)(nt * 16 + col) * S_LEN + kv0 + c * 32 + quad * 8);
                acc_o[nt] = __builtin_amdgcn_mfma_f32_16x16x32_bf16(af, vf, acc_o[nt], 0, 0, 0);
            }
        }
    }

#pragma unroll
    for (int r = 0; r < 4; r++) l_run[r] = 1.0f / l_run[r];
#pragma unroll
    for (int nt = 0; nt < 4; nt++) {
#pragma unroll
        for (int r = 0; r < 4; r++) {
            size_t addr = ((size_t)bh * S_LEN + r0 + quad * 4 + r) * DK + nt * 16 + col;
            Op[addr] = f2bf(acc_o[nt][r] * l_run[r]);
        }
    }
}

// ---------------------------------------------------------------------------
// Final projection: out fp32 = Ap(packed bf16) @ Wot + bo. Grid (8,64), 64x128.
// Register prefetch of next-step A and B.
// ---------------------------------------------------------------------------
__global__ __launch_bounds__(256) void gemm_out(
    const unsigned short* __restrict__ Ap,
    const unsigned short* __restrict__ Wot,
    const float* __restrict__ bo,
    float* __restrict__ out)
{
    __shared__ unsigned short lds_a[64 * 40];

    const int tid  = threadIdx.x;
    const int lane = tid & 63;
    const int wave = tid >> 6;
    const int wm   = wave >> 1;
    const int wn   = wave & 1;
    const int quad = lane >> 4;
    const int col  = lane & 15;
    const int m0   = blockIdx.y * 64;
    const int n0   = blockIdx.x * 128;

    v4f acc[2][4];
#pragma unroll
    for (int i = 0; i < 2; i++)
#pragma unroll
        for (int j = 0; j < 4; j++)
#pragma unroll
            for (int r = 0; r < 4; r++) acc[i][j][r] = 0.0f;

    const int arow = tid >> 2;
    const int achk = (tid & 3) * 8;
    const int tok  = m0 + arow;
    const int bb   = tok >> 11, tt = tok & 2047;

    const unsigned short* bsrc[4];
#pragma unroll
    for (int nt = 0; nt < 4; nt++)
        bsrc[nt] = Wot + (size_t)(n0 + wn * 64 + nt * 16 + col) * D_DIM + quad * 8;

    // prefetch k0=0: A chunk (head h = k0>>6)
    v8s ac = *(const v8s*)(Ap + ((size_t)(bb * NHEAD + 0) * S_LEN + tt) * DK + achk);
    v8s bc[4];
#pragma unroll
    for (int nt = 0; nt < 4; nt++) bc[nt] = *(const v8s*)(bsrc[nt]);

    for (int k0 = 0; k0 < D_DIM; k0 += 32) {
        __syncthreads();
        *(v8s*)(lds_a + arow * 40 + achk) = ac;
        __syncthreads();

        const int kn = (k0 + 32 < D_DIM) ? (k0 + 32) : k0;
        v8s an = *(const v8s*)(Ap + ((size_t)(bb * NHEAD + (kn >> 6)) * S_LEN + tt) * DK + (kn & 63) + achk);
        v8s bn[4];
#pragma unroll
        for (int nt = 0; nt < 4; nt++) bn[nt] = *(const v8s*)(bsrc[nt] + kn);

        v8s af[2];
#pragma unroll
        for (int mt = 0; mt < 2; mt++)
            af[mt] = *(const v8s*)(lds_a + (wm * 32 + mt * 16 + col) * 40 + quad * 8);

#pragma unroll
        for (int mt = 0; mt < 2; mt++)
#pragma unroll
            for (int nt = 0; nt < 4; nt++)
                acc[mt][nt] = __builtin_amdgcn_mfma_f32_16x16x32_bf16(
                    af[mt], bc[nt], acc[mt][nt], 0, 0, 0);

        ac = an;
#pragma unroll
        for (int nt = 0; nt < 4; nt++) bc[nt] = bn[nt];
    }

    float bvv[4];
    int   nn[4];
#pragma unroll
    for (int nt = 0; nt < 4; nt++) {
        nn[nt]  = n0 + wn * 64 + nt * 16 + col;
        bvv[nt] = bo[nn[nt]];
    }

#pragma unroll
    for (int mt = 0; mt < 2; mt++) {
#pragma unroll
        for (int nt = 0; nt < 4; nt++) {
#pragma unroll
            for (int r = 0; r < 4; r++) {
                int row = m0 + wm * 32 + mt * 16 + quad * 4 + r;
                out[(size_t)row * D_DIM + nn[nt]] = acc[mt][nt][r] + bvv[nt];
            }
        }
    }
}

// ---------------------------------------------------------------------------
extern "C" void kernel_launch(void* const* d_in, const int* in_sizes, int n_in,
                              void* d_out, int out_size, void* d_ws, size_t ws_size,
                              hipStream_t stream) {
    const float* q  = (const float*)d_in[0];
    const float* k  = (const float*)d_in[1];
    const float* v  = (const float*)d_in[2];
    const float* Wq = (const float*)d_in[4];
    const float* bq = (const float*)d_in[5];
    const float* Wk = (const float*)d_in[6];
    const float* bk = (const float*)d_in[7];
    const float* Wv = (const float*)d_in[8];
    const float* bv = (const float*)d_in[9];
    const float* Wo = (const float*)d_in[10];
    const float* bo = (const float*)d_in[11];
    float* out = (float*)d_out;

    unsigned short* ws = (unsigned short*)d_ws;
    const size_t WT   = (size_t)D_DIM * D_DIM;
    const size_t TENS = (size_t)M_ROWS * D_DIM;
    unsigned short* Wt = ws;
    unsigned short* Qp = ws + 4 * WT;
    unsigned short* Kp = Qp + TENS;
    unsigned short* Vt = Kp + TENS;
    unsigned short* Ap = Vt + TENS;

    transpose_w<<<dim3(16, 16, 4), 256, 0, stream>>>(Wq, Wk, Wv, Wo, Wt);
    gemm_qkv<<<dim3(8, 32, 3), 256, 0, stream>>>(q, k, v, Wt, bq, bk, bv, Qp, Kp, Vt);
    flash3<<<dim3(128, 32), 64, 0, stream>>>(Qp, Kp, Vt, Ap);
    gemm_out<<<dim3(8, 64), 256, 0, stream>>>(Ap, Wt + 3 * WT, bo, out);
}